// Round 3
// baseline (1521.437 us; speedup 1.0000x reference)
//
#include <hip/hip_runtime.h>
#include <cmath>

typedef unsigned short u16;
typedef unsigned char u8;
typedef unsigned int u32;
typedef float f32x4 __attribute__((ext_vector_type(4)));
typedef int i32x4 __attribute__((ext_vector_type(4)));
typedef short s16x8 __attribute__((ext_vector_type(8)));
typedef u32 u32x4 __attribute__((ext_vector_type(4)));

#define D_MODEL 2048
#define HIDDEN  5461
#define HPAD    5504      // 86*64 = 43*128
#define WCNT    11184128  // HIDDEN*D_MODEL
#define XSCALE  4096.0f

// ---- async global->LDS, 16B per lane (linear dest -> bank-conflict-free) ----
__device__ __forceinline__ void async16(const void* g, void* l) {
  __builtin_amdgcn_global_load_lds(
      (const __attribute__((address_space(1))) unsigned int*)g,
      (__attribute__((address_space(3))) unsigned int*)l, 16, 0, 0);
}

__global__ void zero_sums_kernel(double* __restrict__ s) {
  if (threadIdx.x < 3) s[threadIdx.x] = 0.0;
}

// ---- |w| sum reduction in f64 (decision-boundary-grade precision) ----
__global__ void abssum_kernel(const float* __restrict__ w, long n, double* __restrict__ out) {
  long i0 = ((long)blockIdx.x * blockDim.x + threadIdx.x) * 4;
  long stride = (long)gridDim.x * blockDim.x * 4;
  double s = 0.0;
  for (long i = i0; i < n; i += stride) {
    float4 v = *(const float4*)(w + i);
    s += (double)fabsf(v.x) + (double)fabsf(v.y) + (double)fabsf(v.z) + (double)fabsf(v.w);
  }
#pragma unroll
  for (int off = 32; off > 0; off >>= 1) s += __shfl_down(s, off, 64);
  __shared__ double ls[4];
  int lane = threadIdx.x & 63, wv = threadIdx.x >> 6;
  if (lane == 0) ls[wv] = s;
  __syncthreads();
  if (threadIdx.x == 0) atomicAdd(out, ls[0] + ls[1] + ls[2] + ls[3]);
}

// ---- quantize w1/w3 [HIDDEN, 2048] -> ternary i8 staged [nt 0..42][kg 0..127][col 128][16] ----
__global__ void quant13_kernel(const float* __restrict__ w, const double* __restrict__ sum,
                               char* __restrict__ ws) {
  double s = *sum * (1.0 / (double)WCNT);
  int nt = blockIdx.x;                      // 0..42
  int c  = blockIdx.y * 256 + threadIdx.x;  // 0..16383
  int col = c & 127;
  int kg  = c >> 7;                         // 0..127
  int n = nt * 128 + col;
  u32x4 qv = {0u, 0u, 0u, 0u};
  if (n < HIDDEN) {
    const float* row = w + (long)n * D_MODEL + kg * 16;
#pragma unroll
    for (int q4 = 0; q4 < 4; ++q4) {
      float4 v = *(const float4*)(row + q4 * 4);
      float vv[4] = {v.x, v.y, v.z, v.w};
      u32 word = 0;
#pragma unroll
      for (int e = 0; e < 4; ++e) {
        int qi = (int)fmin(fmax(rint((double)vv[e] / s), -1.0), 1.0);
        word |= ((u32)(u8)(char)qi) << (8 * e);
      }
      qv[q4] = word;
    }
  }
  *(u32x4*)(ws + (long)nt * 262144 + ((long)kg * 128 + col) * 16) = qv;
}

// ---- quantize w2 [2048, HIDDEN] -> ternary i8 staged [nt 0..7][kg 0..343][col 256][16] ----
__global__ void quant2_kernel(const float* __restrict__ w, const double* __restrict__ sum,
                              char* __restrict__ ws) {
  double s = *sum * (1.0 / (double)WCNT);
  int nt = blockIdx.x;           // 0..7
  int kg = blockIdx.y;           // 0..343
  int col = threadIdx.x;         // 0..255
  int n = nt * 256 + col;
  const float* row = w + (long)n * HIDDEN;
  u32x4 qv = {0u, 0u, 0u, 0u};
#pragma unroll
  for (int q4 = 0; q4 < 4; ++q4) {
    u32 word = 0;
#pragma unroll
    for (int e = 0; e < 4; ++e) {
      int k = kg * 16 + q4 * 4 + e;
      int qi = 0;
      if (k < HIDDEN) {
        float v = row[k];
        qi = (int)fmin(fmax(rint((double)v / s), -1.0), 1.0);
      }
      word |= ((u32)(u8)(char)qi) << (8 * e);
    }
    qv[q4] = word;
  }
  *(u32x4*)(ws + (long)nt * 1409024 + ((long)kg * 256 + col) * 16) = qv;
}

// ---- quantize x to i16 = hi8*256 + lo8, stored as two i8 planes in gemm1 tile layout
//      [mt 0..127][kg 0..127][row 0..127][16B] ----
__global__ void xquant_kernel(const float* __restrict__ x, u8* __restrict__ xhi,
                              u8* __restrict__ xlo) {
  int mt = blockIdx.x;                      // 0..127
  int c  = blockIdx.y * 256 + threadIdx.x;  // 0..16383
  int row = c & 127;
  int kg  = c >> 7;                         // 0..127
  const float* src = x + ((long)mt * 128 + row) * D_MODEL + kg * 16;
  u32x4 hv, lv;
#pragma unroll
  for (int q4 = 0; q4 < 4; ++q4) {
    float4 v = *(const float4*)(src + q4 * 4);
    float vv[4] = {v.x, v.y, v.z, v.w};
    u32 hw = 0, lw = 0;
#pragma unroll
    for (int e = 0; e < 4; ++e) {
      float f = fminf(fmaxf(vv[e] * XSCALE, -32639.f), 32639.f);
      int tt = (int)rintf(f) + 128;          // xi = (tt>>8)*256 + ((tt&0xFF)-128), exact
      hw |= ((u32)((tt >> 8) & 0xFF)) << (8 * e);
      lw |= ((u32)((tt ^ 0x80) & 0xFF)) << (8 * e);
    }
    hv[q4] = hw; lv[q4] = lw;
  }
  long o = (long)mt * 262144 + ((long)kg * 128 + row) * 16;
  *(u32x4*)(xhi + o) = hv;
  *(u32x4*)(xlo + o) = lv;
}

// ---- GEMM1: dual-i8 exact int GEMM, fat 64x64 waves (block 128x128), 1 block/CU,
//      triple-buffered LDS, counted vmcnt, 1 barrier/K-step. g -> i16 hi/lo i8 planes ----
__global__ __launch_bounds__(256, 1)
void gemm1_kernel(const u8* __restrict__ xhi, const u8* __restrict__ xlo,
                  const char* __restrict__ w1s, const char* __restrict__ w3s,
                  const double* __restrict__ sums, u8* __restrict__ gshi,
                  u8* __restrict__ gslo, int mt0) {
  // per buffer (32768 B): Ahi@0 [ks4][row128][16], Alo@8192, B1@16384 [ks4][col128][16], B3@24576
  __shared__ alignas(16) u8 L[3 * 32768];
  const int mtl = blockIdx.x;            // 0..63 (local M tile within pass)
  const int ntt = blockIdx.y;            // 0..42
  const int t = threadIdx.x;
  const int lane = t & 63, wave = t >> 6;
  const int wm = wave >> 1, wn = wave & 1;
  const int quad = lane >> 4;
  const int rowA = wm * 64 + (lane & 15);
  const int colB = wn * 64 + (lane & 15);

  i32x4 a1h[4][4], a1l[4][4], a3h[4][4], a3l[4][4];
#pragma unroll
  for (int i = 0; i < 4; ++i)
#pragma unroll
    for (int j = 0; j < 4; ++j) {
      a1h[i][j] = {0, 0, 0, 0}; a1l[i][j] = {0, 0, 0, 0};
      a3h[i][j] = {0, 0, 0, 0}; a3l[i][j] = {0, 0, 0, 0};
    }

  const u8* Ah = xhi + (long)(mt0 + mtl) * 262144 + t * 16;
  const u8* Al = xlo + (long)(mt0 + mtl) * 262144 + t * 16;
  const char* B1 = w1s + (long)ntt * 262144 + t * 16;
  const char* B3 = w3s + (long)ntt * 262144 + t * 16;

#define STAGE1(buf, c) do {                                      \
    u8* Lb_ = L + (buf) * 32768;                                 \
    async16(Ah + (c) * 8192,        Lb_ + t * 16);               \
    async16(Ah + (c) * 8192 + 4096, Lb_ + 4096 + t * 16);        \
    async16(Al + (c) * 8192,        Lb_ + 8192 + t * 16);        \
    async16(Al + (c) * 8192 + 4096, Lb_ + 12288 + t * 16);       \
    async16(B1 + (c) * 8192,        Lb_ + 16384 + t * 16);       \
    async16(B1 + (c) * 8192 + 4096, Lb_ + 20480 + t * 16);       \
    async16(B3 + (c) * 8192,        Lb_ + 24576 + t * 16);       \
    async16(B3 + (c) * 8192 + 4096, Lb_ + 28672 + t * 16);       \
  } while (0)

  STAGE1(0, 0);
  int cur = 0;
  for (int c = 0; c < 32; ++c) {
    int nb = cur + 1; if (nb == 3) nb = 0;
    if (c < 31) {
      STAGE1(nb, c + 1);
      // wait only the OLDEST 8 loads (tile c); tile c+1's 8 stay in flight across barrier
      asm volatile("s_waitcnt vmcnt(8)" ::: "memory");
    } else {
      asm volatile("s_waitcnt vmcnt(0)" ::: "memory");
    }
    __builtin_amdgcn_s_barrier();
    const u8* Lb = L + cur * 32768;
    i32x4 ah[4], al[4], b1f[4], b3f[4];
#pragma unroll
    for (int j = 0; j < 4; ++j) {
      b1f[j] = *(const i32x4*)&Lb[16384 + (quad * 128 + colB + j * 16) * 16];
      b3f[j] = *(const i32x4*)&Lb[24576 + (quad * 128 + colB + j * 16) * 16];
    }
#pragma unroll
    for (int i = 0; i < 4; ++i) {
      ah[i] = *(const i32x4*)&Lb[(quad * 128 + rowA + i * 16) * 16];
      al[i] = *(const i32x4*)&Lb[8192 + (quad * 128 + rowA + i * 16) * 16];
    }
    __builtin_amdgcn_s_setprio(1);
#pragma unroll
    for (int i = 0; i < 4; ++i)
#pragma unroll
      for (int j = 0; j < 4; ++j) {
        a1h[i][j] = __builtin_amdgcn_mfma_i32_16x16x64_i8(ah[i], b1f[j], a1h[i][j], 0, 0, 0);
        a1l[i][j] = __builtin_amdgcn_mfma_i32_16x16x64_i8(al[i], b1f[j], a1l[i][j], 0, 0, 0);
        a3h[i][j] = __builtin_amdgcn_mfma_i32_16x16x64_i8(ah[i], b3f[j], a3h[i][j], 0, 0, 0);
        a3l[i][j] = __builtin_amdgcn_mfma_i32_16x16x64_i8(al[i], b3f[j], a3l[i][j], 0, 0, 0);
      }
    __builtin_amdgcn_s_setprio(0);
    cur = nb;
  }
#undef STAGE1

  const float sc1 = (float)(sums[0] * (1.0 / (double)WCNT)) / XSCALE;
  const float sc3 = (float)(sums[1] * (1.0 / (double)WCNT)) / XSCALE;
  u8* gh = gshi + (long)mtl * 704512;
  u8* gl = gslo + (long)mtl * 704512;
#pragma unroll
  for (int i = 0; i < 4; ++i) {
#pragma unroll
    for (int j = 0; j < 4; ++j) {
      const int h = ntt * 128 + wn * 64 + j * 16 + (lane & 15);
      const long cbase = ((long)(h >> 4) * 128) * 16 + (h & 15);
#pragma unroll
      for (int rr = 0; rr < 4; ++rr) {
        const int mm = wm * 64 + i * 16 + quad * 4 + rr;
        float h1 = (float)(a1h[i][j][rr] * 256 + a1l[i][j][rr]) * sc1;
        float h3 = (float)(a3h[i][j][rr] * 256 + a3l[i][j][rr]) * sc3;
        float g = (h1 / (1.0f + expf(-h1))) * h3;
        float f = fminf(fmaxf(g * XSCALE, -32639.f), 32639.f);
        int tt2 = (int)rintf(f) + 128;
        long off = cbase + (long)mm * 16;
        gh[off] = (u8)((tt2 >> 8) & 0xFF);
        gl[off] = (u8)((tt2 ^ 0x80) & 0xFF);
      }
    }
  }
}

// ---- GEMM2: dual-i8(A=g) x single-i8(B=w2) exact int GEMM, K=5504.
//      fat 64x128 waves (block 128x256), 1 block/CU, triple-buffered, counted vmcnt ----
__global__ __launch_bounds__(256, 1)
void gemm2_kernel(const u8* __restrict__ gshi, const u8* __restrict__ gslo,
                  const char* __restrict__ w2s, const double* __restrict__ sums,
                  float* __restrict__ out) {
  // per buffer (32768 B): Ahi@0 [ks4][row128][16], Alo@8192, B@16384 [ks4][col256][16]
  __shared__ alignas(16) u8 L[3 * 32768];
  const int mtl = blockIdx.x;            // 0..63
  const int ntt = blockIdx.y;            // 0..7
  const int t = threadIdx.x;
  const int lane = t & 63, wave = t >> 6;
  const int wm = wave >> 1, wn = wave & 1;
  const int quad = lane >> 4;
  const int rowA = wm * 64 + (lane & 15);
  const int colB = wn * 128 + (lane & 15);

  i32x4 ach[4][8], acl[4][8];
#pragma unroll
  for (int i = 0; i < 4; ++i)
#pragma unroll
    for (int j = 0; j < 8; ++j) {
      ach[i][j] = {0, 0, 0, 0}; acl[i][j] = {0, 0, 0, 0};
    }

  const u8* Ahg = gshi + (long)mtl * 704512 + t * 16;
  const u8* Alg = gslo + (long)mtl * 704512 + t * 16;
  const char* Bw = w2s + (long)ntt * 1409024 + t * 16;

#define STAGE2(buf, c) do {                                      \
    u8* Lb_ = L + (buf) * 32768;                                 \
    async16(Ahg + (c) * 8192,         Lb_ + t * 16);             \
    async16(Ahg + (c) * 8192 + 4096,  Lb_ + 4096 + t * 16);      \
    async16(Alg + (c) * 8192,         Lb_ + 8192 + t * 16);      \
    async16(Alg + (c) * 8192 + 4096,  Lb_ + 12288 + t * 16);     \
    async16(Bw + (c) * 16384,         Lb_ + 16384 + t * 16);     \
    async16(Bw + (c) * 16384 + 4096,  Lb_ + 20480 + t * 16);     \
    async16(Bw + (c) * 16384 + 8192,  Lb_ + 24576 + t * 16);     \
    async16(Bw + (c) * 16384 + 12288, Lb_ + 28672 + t * 16);     \
  } while (0)

  STAGE2(0, 0);
  int cur = 0;
  for (int c = 0; c < 86; ++c) {
    int nb = cur + 1; if (nb == 3) nb = 0;
    if (c < 85) {
      STAGE2(nb, c + 1);
      asm volatile("s_waitcnt vmcnt(8)" ::: "memory");
    } else {
      asm volatile("s_waitcnt vmcnt(0)" ::: "memory");
    }
    __builtin_amdgcn_s_barrier();
    const u8* Lb = L + cur * 32768;
    i32x4 ah[4], al[4], bw[8];
#pragma unroll
    for (int j = 0; j < 8; ++j)
      bw[j] = *(const i32x4*)&Lb[16384 + (quad * 256 + colB + j * 16) * 16];
#pragma unroll
    for (int i = 0; i < 4; ++i) {
      ah[i] = *(const i32x4*)&Lb[(quad * 128 + rowA + i * 16) * 16];
      al[i] = *(const i32x4*)&Lb[8192 + (quad * 128 + rowA + i * 16) * 16];
    }
    __builtin_amdgcn_s_setprio(1);
#pragma unroll
    for (int i = 0; i < 4; ++i)
#pragma unroll
      for (int j = 0; j < 8; ++j) {
        ach[i][j] = __builtin_amdgcn_mfma_i32_16x16x64_i8(ah[i], bw[j], ach[i][j], 0, 0, 0);
        acl[i][j] = __builtin_amdgcn_mfma_i32_16x16x64_i8(al[i], bw[j], acl[i][j], 0, 0, 0);
      }
    __builtin_amdgcn_s_setprio(0);
    cur = nb;
  }
#undef STAGE2

  const float s2g = (float)(sums[2] * (1.0 / (double)WCNT)) / XSCALE;
#pragma unroll
  for (int i = 0; i < 4; ++i) {
#pragma unroll
    for (int j = 0; j < 8; ++j) {
      const int d = ntt * 256 + wn * 128 + j * 16 + (lane & 15);
#pragma unroll
      for (int rr = 0; rr < 4; ++rr) {
        const long m = (long)mtl * 128 + wm * 64 + i * 16 + quad * 4 + rr;
        int v = ach[i][j][rr] * 256 + acl[i][j][rr];
        out[m * D_MODEL + d] = (float)v * s2g;
      }
    }
  }
}

extern "C" void kernel_launch(void* const* d_in, const int* in_sizes, int n_in,
                              void* d_out, int out_size, void* d_ws, size_t ws_size,
                              hipStream_t stream) {
  (void)in_sizes; (void)n_in; (void)out_size; (void)ws_size;
  const float* x  = (const float*)d_in[0];
  const float* w1 = (const float*)d_in[1];
  const float* w3 = (const float*)d_in[2];
  const float* w2 = (const float*)d_in[3];
  float* out = (float*)d_out;

  // workspace layout (total ~191 MiB):
  //   sums: 3 f64 (256 B slot)
  //   w1s/w3s: i8 ternary [43][128][128][16] = 11,272,192 B each
  //   w2s:     i8 ternary [8][344][256][16]  = 11,272,192 B
  //   xhi/xlo: i8 planes [128][128][128][16] = 33,554,432 B each
  //   gshi/gslo: i8 HALF-M [64][344][128][16] = 45,088,768 B each (reused across 2 passes)
  char* ws = (char*)d_ws;
  double* sums = (double*)ws;
  char* w1s = ws + 256;
  char* w3s = w1s + 11272192L;
  char* w2s = w3s + 11272192L;
  u8*   xhi = (u8*)(w2s + 11272192L);
  u8*   xlo = xhi + 33554432L;
  u8*   gshi = xlo + 33554432L;
  u8*   gslo = gshi + 45088768L;

  zero_sums_kernel<<<1, 64, 0, stream>>>(sums);
  abssum_kernel<<<1024, 256, 0, stream>>>(w1, (long)WCNT, sums + 0);
  abssum_kernel<<<1024, 256, 0, stream>>>(w3, (long)WCNT, sums + 1);
  abssum_kernel<<<1024, 256, 0, stream>>>(w2, (long)WCNT, sums + 2);

  quant13_kernel<<<dim3(43, 64), 256, 0, stream>>>(w1, sums + 0, w1s);
  quant13_kernel<<<dim3(43, 64), 256, 0, stream>>>(w3, sums + 1, w3s);
  quant2_kernel<<<dim3(8, 344), 256, 0, stream>>>(w2, sums + 2, w2s);
  xquant_kernel<<<dim3(128, 64), 256, 0, stream>>>(x, xhi, xlo);

  for (int pass = 0; pass < 2; ++pass) {
    gemm1_kernel<<<dim3(64, 43), 256, 0, stream>>>(xhi, xlo, w1s, w3s, sums,
                                                   gshi, gslo, pass * 64);
    gemm2_kernel<<<dim3(64, 8), 256, 0, stream>>>(gshi, gslo, w2s, sums,
                                                  out + (long)pass * 64 * 128 * D_MODEL);
  }
}

// Round 4
// 1334.375 us; speedup vs baseline: 1.1402x; 1.1402x over previous
//
#include <hip/hip_runtime.h>
#include <cmath>

typedef unsigned short u16;
typedef unsigned char u8;
typedef unsigned int u32;
typedef float f32x4 __attribute__((ext_vector_type(4)));
typedef int i32x4 __attribute__((ext_vector_type(4)));
typedef short s16x8 __attribute__((ext_vector_type(8)));
typedef u32 u32x4 __attribute__((ext_vector_type(4)));

#define D_MODEL 2048
#define HIDDEN  5461
#define HPAD    5504      // 86*64 = 344*16
#define WCNT    11184128  // HIDDEN*D_MODEL
#define XSCALE  4096.0f

// ---- async global->LDS, 16B per lane (linear dest -> bank-conflict-free) ----
__device__ __forceinline__ void async16(const void* g, void* l) {
  __builtin_amdgcn_global_load_lds(
      (const __attribute__((address_space(1))) unsigned int*)g,
      (__attribute__((address_space(3))) unsigned int*)l, 16, 0, 0);
}

__global__ void zero_sums_kernel(double* __restrict__ s) {
  if (threadIdx.x < 3) s[threadIdx.x] = 0.0;
}

// ---- |w| sum reduction in f64 (decision-boundary-grade precision) ----
__global__ void abssum_kernel(const float* __restrict__ w, long n, double* __restrict__ out) {
  long i0 = ((long)blockIdx.x * blockDim.x + threadIdx.x) * 4;
  long stride = (long)gridDim.x * blockDim.x * 4;
  double s = 0.0;
  for (long i = i0; i < n; i += stride) {
    float4 v = *(const float4*)(w + i);
    s += (double)fabsf(v.x) + (double)fabsf(v.y) + (double)fabsf(v.z) + (double)fabsf(v.w);
  }
#pragma unroll
  for (int off = 32; off > 0; off >>= 1) s += __shfl_down(s, off, 64);
  __shared__ double ls[4];
  int lane = threadIdx.x & 63, wv = threadIdx.x >> 6;
  if (lane == 0) ls[wv] = s;
  __syncthreads();
  if (threadIdx.x == 0) atomicAdd(out, ls[0] + ls[1] + ls[2] + ls[3]);
}

// ---- quantize w1/w3 [HIDDEN, 2048] -> ternary i8 staged [nt 0..85][kg 0..127][col 64][16] ----
__global__ void quant13_kernel(const float* __restrict__ w, const double* __restrict__ sum,
                               char* __restrict__ ws) {
  double s = *sum * (1.0 / (double)WCNT);
  int nt = blockIdx.x;                      // 0..85
  int c  = blockIdx.y * 256 + threadIdx.x;  // 0..8191
  int col = c & 63;
  int kg  = c >> 6;                         // 0..127
  int n = nt * 64 + col;
  u32x4 qv = {0u, 0u, 0u, 0u};
  if (n < HIDDEN) {
    const float* row = w + (long)n * D_MODEL + kg * 16;
#pragma unroll
    for (int q4 = 0; q4 < 4; ++q4) {
      float4 v = *(const float4*)(row + q4 * 4);
      float vv[4] = {v.x, v.y, v.z, v.w};
      u32 word = 0;
#pragma unroll
      for (int e = 0; e < 4; ++e) {
        int qi = (int)fmin(fmax(rint((double)vv[e] / s), -1.0), 1.0);
        word |= ((u32)(u8)(char)qi) << (8 * e);
      }
      qv[q4] = word;
    }
  }
  *(u32x4*)(ws + (long)nt * 131072 + ((long)kg * 64 + col) * 16) = qv;
}

// ---- quantize w2 [2048, HIDDEN] -> ternary i8 staged [nt 0..31][kg 0..343][col 64][16] ----
__global__ void quant2_kernel(const float* __restrict__ w, const double* __restrict__ sum,
                              char* __restrict__ ws) {
  double s = *sum * (1.0 / (double)WCNT);
  int nt = blockIdx.x;           // 0..31 (d-tile of 64)
  int kg = blockIdx.y;           // 0..343
  int col = threadIdx.x & 63;    // d within tile
  int q4  = threadIdx.x >> 6;    // 0..3 (4 bytes each)
  int n = nt * 64 + col;
  const float* row = w + (long)n * HIDDEN;
  u32 word = 0;
#pragma unroll
  for (int e = 0; e < 4; ++e) {
    int k = kg * 16 + q4 * 4 + e;
    int qi = 0;
    if (k < HIDDEN) {
      float v = row[k];
      qi = (int)fmin(fmax(rint((double)v / s), -1.0), 1.0);
    }
    word |= ((u32)(u8)(char)qi) << (8 * e);
  }
  *(u32*)(ws + (long)nt * 352256 + ((long)kg * 64 + col) * 16 + q4 * 4) = word;
}

// ---- quantize x to i16 = hi8*256 + lo8, stored as two i8 planes in gemm1 tile layout
//      [mt 0..127][kg 0..127][row 0..127][16B] ----
__global__ void xquant_kernel(const float* __restrict__ x, u8* __restrict__ xhi,
                              u8* __restrict__ xlo) {
  int mt = blockIdx.x;                      // 0..127
  int c  = blockIdx.y * 256 + threadIdx.x;  // 0..16383
  int row = c & 127;
  int kg  = c >> 7;                         // 0..127
  const float* src = x + ((long)mt * 128 + row) * D_MODEL + kg * 16;
  u32x4 hv, lv;
#pragma unroll
  for (int q4 = 0; q4 < 4; ++q4) {
    float4 v = *(const float4*)(src + q4 * 4);
    float vv[4] = {v.x, v.y, v.z, v.w};
    u32 hw = 0, lw = 0;
#pragma unroll
    for (int e = 0; e < 4; ++e) {
      float f = fminf(fmaxf(vv[e] * XSCALE, -32639.f), 32639.f);
      int tt = (int)rintf(f) + 128;          // xi = (tt>>8)*256 + ((tt&0xFF)-128), exact
      hw |= ((u32)((tt >> 8) & 0xFF)) << (8 * e);
      lw |= ((u32)((tt ^ 0x80) & 0xFF)) << (8 * e);
    }
    hv[q4] = hw; lv[q4] = lw;
  }
  long o = (long)mt * 262144 + ((long)kg * 128 + row) * 16;
  *(u32x4*)(xhi + o) = hv;
  *(u32x4*)(xlo + o) = lv;
}

// ---- GEMM1: dual-i8 exact int GEMM, block 128x64, 4 waves of 64x32, 2 blocks/CU,
//      triple-buffered LDS, counted vmcnt, 1 barrier/K-step. g -> i16 hi/lo i8 planes ----
__global__ __launch_bounds__(256, 2)
void gemm1_kernel(const u8* __restrict__ xhi, const u8* __restrict__ xlo,
                  const char* __restrict__ w1s, const char* __restrict__ w3s,
                  const double* __restrict__ sums, u8* __restrict__ gshi,
                  u8* __restrict__ gslo, int mt0) {
  // per buffer (24576 B): Ahi@0 [kgl4][row128][16], Alo@8192, B1@16384 [kgl4][col64][16], B3@20480
  __shared__ alignas(16) u8 L[3 * 24576];
  const int mtl = blockIdx.x;            // 0..63 (local M tile within pass)
  const int nt  = blockIdx.y;            // 0..85
  const int mtg = mt0 + mtl;
  const int t = threadIdx.x;
  const int lane = t & 63, wave = t >> 6;
  const int wm = wave >> 1, wn = wave & 1;
  const int quad = lane >> 4;
  const int rowA = wm * 64 + (lane & 15);
  const int rowB = wn * 32 + (lane & 15);

  i32x4 a1h[4][2], a1l[4][2], a3h[4][2], a3l[4][2];
#pragma unroll
  for (int i = 0; i < 4; ++i)
#pragma unroll
    for (int j = 0; j < 2; ++j) {
      a1h[i][j] = {0, 0, 0, 0}; a1l[i][j] = {0, 0, 0, 0};
      a3h[i][j] = {0, 0, 0, 0}; a3l[i][j] = {0, 0, 0, 0};
    }

  const u8* Ah = xhi + (long)mtg * 262144 + t * 16;
  const u8* Al = xlo + (long)mtg * 262144 + t * 16;
  const char* B1 = w1s + (long)nt * 131072 + t * 16;
  const char* B3 = w3s + (long)nt * 131072 + t * 16;

#define STAGE1(buf, c) do {                                      \
    u8* Lb_ = L + (buf) * 24576;                                 \
    async16(Ah + (c) * 8192,        Lb_ + t * 16);               \
    async16(Ah + (c) * 8192 + 4096, Lb_ + 4096 + t * 16);        \
    async16(Al + (c) * 8192,        Lb_ + 8192 + t * 16);        \
    async16(Al + (c) * 8192 + 4096, Lb_ + 12288 + t * 16);       \
    async16(B1 + (c) * 4096,        Lb_ + 16384 + t * 16);       \
    async16(B3 + (c) * 4096,        Lb_ + 20480 + t * 16);       \
  } while (0)

  STAGE1(0, 0);
  int cur = 0;
  for (int c = 0; c < 32; ++c) {
    int nb = cur + 1; if (nb == 3) nb = 0;
    if (c < 31) {
      STAGE1(nb, c + 1);
      // wait only the OLDEST 6 loads (tile c); tile c+1's 6 stay in flight across barrier
      asm volatile("s_waitcnt vmcnt(6)" ::: "memory");
    } else {
      asm volatile("s_waitcnt vmcnt(0)" ::: "memory");
    }
    __builtin_amdgcn_s_barrier();
    const u8* Lb = L + cur * 24576;
    i32x4 b1f[2], b3f[2], ah[4], al[4];
#pragma unroll
    for (int j = 0; j < 2; ++j) {
      b1f[j] = *(const i32x4*)&Lb[16384 + quad * 1024 + (rowB + j * 16) * 16];
      b3f[j] = *(const i32x4*)&Lb[20480 + quad * 1024 + (rowB + j * 16) * 16];
    }
#pragma unroll
    for (int i = 0; i < 4; ++i) {
      ah[i] = *(const i32x4*)&Lb[quad * 2048 + (rowA + i * 16) * 16];
      al[i] = *(const i32x4*)&Lb[8192 + quad * 2048 + (rowA + i * 16) * 16];
    }
    __builtin_amdgcn_s_setprio(1);
#pragma unroll
    for (int i = 0; i < 4; ++i)
#pragma unroll
      for (int j = 0; j < 2; ++j) {
        a1h[i][j] = __builtin_amdgcn_mfma_i32_16x16x64_i8(ah[i], b1f[j], a1h[i][j], 0, 0, 0);
        a1l[i][j] = __builtin_amdgcn_mfma_i32_16x16x64_i8(al[i], b1f[j], a1l[i][j], 0, 0, 0);
        a3h[i][j] = __builtin_amdgcn_mfma_i32_16x16x64_i8(ah[i], b3f[j], a3h[i][j], 0, 0, 0);
        a3l[i][j] = __builtin_amdgcn_mfma_i32_16x16x64_i8(al[i], b3f[j], a3l[i][j], 0, 0, 0);
      }
    __builtin_amdgcn_s_setprio(0);
    cur = nb;
  }
#undef STAGE1

  const float sc1 = (float)(sums[0] * (1.0 / (double)WCNT)) / XSCALE;
  const float sc3 = (float)(sums[1] * (1.0 / (double)WCNT)) / XSCALE;
  u8* gh = gshi + (long)mtl * 704512;
  u8* gl = gslo + (long)mtl * 704512;
#pragma unroll
  for (int i = 0; i < 4; ++i) {
#pragma unroll
    for (int j = 0; j < 2; ++j) {
      const int h = nt * 64 + wn * 32 + j * 16 + (lane & 15);
      const long cbase = ((long)(h >> 4) * 128) * 16 + (h & 15);
#pragma unroll
      for (int rr = 0; rr < 4; ++rr) {
        const int mm = wm * 64 + i * 16 + quad * 4 + rr;
        float h1 = (float)(a1h[i][j][rr] * 256 + a1l[i][j][rr]) * sc1;
        float h3 = (float)(a3h[i][j][rr] * 256 + a3l[i][j][rr]) * sc3;
        float g = (h1 / (1.0f + expf(-h1))) * h3;
        float f = fminf(fmaxf(g * XSCALE, -32639.f), 32639.f);
        int tt2 = (int)rintf(f) + 128;
        long off = cbase + (long)mm * 16;
        gh[off] = (u8)((tt2 >> 8) & 0xFF);
        gl[off] = (u8)((tt2 ^ 0x80) & 0xFF);
      }
    }
  }
}

// ---- GEMM2: dual-i8(A=g hi/lo) x single-i8(B=w2) exact int GEMM, K=5504, BK=64.
//      block 128x64, 4 waves of 64x32, 2 blocks/CU, triple-buffered, counted vmcnt ----
__global__ __launch_bounds__(256, 2)
void gemm2_kernel(const u8* __restrict__ gshi, const u8* __restrict__ gslo,
                  const char* __restrict__ w2s, const double* __restrict__ sums,
                  float* __restrict__ out) {
  // per buffer (20480 B): Ahi@0 [kg4][row128][16], Alo@8192, B@16384 [kg4][col64][16]
  __shared__ alignas(16) u8 L[3 * 20480];
  const int ntt = blockIdx.x;            // 0..31 (fast: blocks sharing A-panel spread per XCD)
  const int mtl = blockIdx.y;            // 0..63
  const int t = threadIdx.x;
  const int lane = t & 63, wave = t >> 6;
  const int wm = wave >> 1, wn = wave & 1;
  const int quad = lane >> 4;
  const int rowA = wm * 64 + (lane & 15);
  const int colB = wn * 32 + (lane & 15);

  i32x4 ach[4][2], acl[4][2];
#pragma unroll
  for (int i = 0; i < 4; ++i)
#pragma unroll
    for (int j = 0; j < 2; ++j) {
      ach[i][j] = {0, 0, 0, 0}; acl[i][j] = {0, 0, 0, 0};
    }

  const u8* Ahg = gshi + (long)mtl * 704512 + t * 16;
  const u8* Alg = gslo + (long)mtl * 704512 + t * 16;
  const char* Bw = w2s + (long)ntt * 352256 + t * 16;

#define STAGE2(buf, c) do {                                      \
    u8* Lb_ = L + (buf) * 20480;                                 \
    async16(Ahg + (c) * 8192,        Lb_ + t * 16);              \
    async16(Ahg + (c) * 8192 + 4096, Lb_ + 4096 + t * 16);       \
    async16(Alg + (c) * 8192,        Lb_ + 8192 + t * 16);       \
    async16(Alg + (c) * 8192 + 4096, Lb_ + 12288 + t * 16);     \
    async16(Bw + (c) * 4096,         Lb_ + 16384 + t * 16);      \
  } while (0)

  STAGE2(0, 0);
  int cur = 0;
  for (int c = 0; c < 86; ++c) {
    int nb = cur + 1; if (nb == 3) nb = 0;
    if (c < 85) {
      STAGE2(nb, c + 1);
      asm volatile("s_waitcnt vmcnt(5)" ::: "memory");
    } else {
      asm volatile("s_waitcnt vmcnt(0)" ::: "memory");
    }
    __builtin_amdgcn_s_barrier();
    const u8* Lb = L + cur * 20480;
    i32x4 ah[4], al[4], bw[2];
#pragma unroll
    for (int j = 0; j < 2; ++j)
      bw[j] = *(const i32x4*)&Lb[16384 + quad * 1024 + (colB + j * 16) * 16];
#pragma unroll
    for (int i = 0; i < 4; ++i) {
      ah[i] = *(const i32x4*)&Lb[quad * 2048 + (rowA + i * 16) * 16];
      al[i] = *(const i32x4*)&Lb[8192 + quad * 2048 + (rowA + i * 16) * 16];
    }
    __builtin_amdgcn_s_setprio(1);
#pragma unroll
    for (int i = 0; i < 4; ++i)
#pragma unroll
      for (int j = 0; j < 2; ++j) {
        ach[i][j] = __builtin_amdgcn_mfma_i32_16x16x64_i8(ah[i], bw[j], ach[i][j], 0, 0, 0);
        acl[i][j] = __builtin_amdgcn_mfma_i32_16x16x64_i8(al[i], bw[j], acl[i][j], 0, 0, 0);
      }
    __builtin_amdgcn_s_setprio(0);
    cur = nb;
  }
#undef STAGE2

  const float s2g = (float)(sums[2] * (1.0 / (double)WCNT)) / XSCALE;
#pragma unroll
  for (int i = 0; i < 4; ++i) {
#pragma unroll
    for (int j = 0; j < 2; ++j) {
      const int d = ntt * 64 + wn * 32 + j * 16 + (lane & 15);
#pragma unroll
      for (int rr = 0; rr < 4; ++rr) {
        const long m = (long)mtl * 128 + wm * 64 + i * 16 + quad * 4 + rr;
        int v = ach[i][j][rr] * 256 + acl[i][j][rr];
        out[m * D_MODEL + d] = (float)v * s2g;
      }
    }
  }
}

extern "C" void kernel_launch(void* const* d_in, const int* in_sizes, int n_in,
                              void* d_out, int out_size, void* d_ws, size_t ws_size,
                              hipStream_t stream) {
  (void)in_sizes; (void)n_in; (void)out_size; (void)ws_size;
  const float* x  = (const float*)d_in[0];
  const float* w1 = (const float*)d_in[1];
  const float* w3 = (const float*)d_in[2];
  const float* w2 = (const float*)d_in[3];
  float* out = (float*)d_out;

  // workspace layout (total ~191 MiB):
  //   sums: 3 f64 (256 B slot)
  //   w1s/w3s: i8 ternary [86][128][64][16] = 11,272,192 B each
  //   w2s:     i8 ternary [32][344][64][16] = 11,272,192 B
  //   xhi/xlo: i8 planes [128][128][128][16] = 33,554,432 B each
  //   gshi/gslo: i8 HALF-M [64][344][128][16] = 45,088,768 B each (reused across 2 passes)
  char* ws = (char*)d_ws;
  double* sums = (double*)ws;
  char* w1s = ws + 256;
  char* w3s = w1s + 11272192L;
  char* w2s = w3s + 11272192L;
  u8*   xhi = (u8*)(w2s + 11272192L);
  u8*   xlo = xhi + 33554432L;
  u8*   gshi = xlo + 33554432L;
  u8*   gslo = gshi + 45088768L;

  zero_sums_kernel<<<1, 64, 0, stream>>>(sums);
  abssum_kernel<<<1024, 256, 0, stream>>>(w1, (long)WCNT, sums + 0);
  abssum_kernel<<<1024, 256, 0, stream>>>(w3, (long)WCNT, sums + 1);
  abssum_kernel<<<1024, 256, 0, stream>>>(w2, (long)WCNT, sums + 2);

  quant13_kernel<<<dim3(86, 32), 256, 0, stream>>>(w1, sums + 0, w1s);
  quant13_kernel<<<dim3(86, 32), 256, 0, stream>>>(w3, sums + 1, w3s);
  quant2_kernel<<<dim3(32, 344), 256, 0, stream>>>(w2, sums + 2, w2s);
  xquant_kernel<<<dim3(128, 64), 256, 0, stream>>>(x, xhi, xlo);

  for (int pass = 0; pass < 2; ++pass) {
    gemm1_kernel<<<dim3(64, 86), 256, 0, stream>>>(xhi, xlo, w1s, w3s, sums,
                                                   gshi, gslo, pass * 64);
    gemm2_kernel<<<dim3(32, 64), 256, 0, stream>>>(gshi, gslo, w2s, sums,
                                                   out + (long)pass * 64 * 128 * D_MODEL);
  }
}